// Round 4
// baseline (355.961 us; speedup 1.0000x reference)
//
#include <hip/hip_runtime.h>
#include <hip/hip_bf16.h>

typedef short s16x8 __attribute__((ext_vector_type(8)));
typedef float f32x4 __attribute__((ext_vector_type(4)));
typedef float f32x2 __attribute__((ext_vector_type(2)));

#define MFMA_BF16(A, B, C) __builtin_amdgcn_mfma_f32_16x16x32_bf16(A, B, C, 0, 0, 0)

constexpr int Bn = 4, Tn = 2048, Cn = 1024, Hn = 16, Dn = 64;
constexpr int Mn = Bn * Tn;      // 8192
constexpr int Nqkv = 3 * Cn;     // 3072
constexpr float SC = 0.125f * 1.44269504089f;  // 1/sqrt(D) * log2(e)

__device__ __forceinline__ ushort f2bfu(float f) {
    __hip_bfloat16 h = __float2bfloat16(f);
    return *reinterpret_cast<ushort*>(&h);
}
__device__ __forceinline__ uint pkbf(float a, float b) {
    __hip_bfloat162 h = __float22bfloat162_rn(make_float2(a, b));
    return *reinterpret_cast<uint*>(&h);
}

// packed fp32 VALU (full-rate on CDNA4)
__device__ __forceinline__ f32x2 pk_add(f32x2 a, f32x2 b) {
    f32x2 d; asm("v_pk_add_f32 %0, %1, %2" : "=v"(d) : "v"(a), "v"(b)); return d;
}
__device__ __forceinline__ f32x2 pk_mul(f32x2 a, f32x2 b) {
    f32x2 d; asm("v_pk_mul_f32 %0, %1, %2" : "=v"(d) : "v"(a), "v"(b)); return d;
}

// async global->LDS, 16B per lane; LDS dest = wave-uniform base + lane*16.
__device__ __forceinline__ void gl_lds16(const void* g, void* l) {
    __builtin_amdgcn_global_load_lds(
        (const __attribute__((address_space(1))) void*)(uintptr_t)g,
        (__attribute__((address_space(3))) void*)(uint32_t)(uintptr_t)l,
        16, 0, 0);
}

// ---------------------------------------------------------------------------
// fp32 -> bf16 elementwise (x)
// ---------------------------------------------------------------------------
__global__ __launch_bounds__(256) void conv_bf16_kernel(
    const float* __restrict__ src, ushort* __restrict__ dst, int n4)
{
    int i = blockIdx.x * blockDim.x + threadIdx.x;
    int stride = gridDim.x * blockDim.x;
    for (; i < n4; i += stride) {
        float4 v = ((const float4*)src)[i];
        ushort4 o;
        o.x = f2bfu(v.x); o.y = f2bfu(v.y); o.z = f2bfu(v.z); o.w = f2bfu(v.w);
        ((ushort4*)dst)[i] = o;
    }
}

// ---------------------------------------------------------------------------
// W [K][N] fp32  ->  Wt [N][K] bf16   (64x64 tiles via LDS)
// ---------------------------------------------------------------------------
__global__ __launch_bounds__(256) void transpose_cvt_kernel(
    const float* __restrict__ W, ushort* __restrict__ Wt, int K, int N)
{
    __shared__ __align__(16) float Ls[64][68];
    const int t = threadIdx.x;
    const int n0 = blockIdx.x * 64, k0 = blockIdx.y * 64;
#pragma unroll
    for (int p = 0; p < 4; ++p) {
        int r = (t >> 4) + p * 16;
        int c = (t & 15) * 4;
        *(float4*)&Ls[r][c] = *(const float4*)&W[(size_t)(k0 + r) * N + n0 + c];
    }
    __syncthreads();
    const int n = t >> 2;
    const int ks = (t & 3) * 16;
    union { ushort s[16]; uint4 u[2]; } tmp;
#pragma unroll
    for (int j = 0; j < 16; ++j) tmp.s[j] = f2bfu(Ls[ks + j][n]);
    uint4* dp = (uint4*)&Wt[(size_t)(n0 + n) * K + k0 + ks];
    dp[0] = tmp.u[0];
    dp[1] = tmp.u[1];
}

// ---------------------------------------------------------------------------
// V [bh][t][d] bf16 -> Vt [bh][d][t] bf16 (4x4 in-register transpose)
// ---------------------------------------------------------------------------
__global__ __launch_bounds__(256) void vt_transpose_kernel(
    const ushort* __restrict__ V, ushort* __restrict__ Vt)
{
    const int tid = threadIdx.x;
    const int bh = blockIdx.x;
    const int kt0 = blockIdx.y * 64;
    const ushort* src = V + (size_t)bh * Tn * Dn;
    ushort* dst = Vt + (size_t)bh * Dn * Tn;
    const int vk = (tid & 15) * 4, vd = (tid >> 4) * 4;
    const ushort* g = src + (size_t)(kt0 + vk) * Dn + vd;
    ushort4 v0 = *(const ushort4*)(g);
    ushort4 v1 = *(const ushort4*)(g + Dn);
    ushort4 v2 = *(const ushort4*)(g + 2 * Dn);
    ushort4 v3 = *(const ushort4*)(g + 3 * Dn);
    ushort4 t0, t1, t2, t3;
    t0.x = v0.x; t0.y = v1.x; t0.z = v2.x; t0.w = v3.x;
    t1.x = v0.y; t1.y = v1.y; t1.z = v2.y; t1.w = v3.y;
    t2.x = v0.z; t2.y = v1.z; t2.z = v2.z; t2.w = v3.z;
    t3.x = v0.w; t3.y = v1.w; t3.z = v2.w; t3.w = v3.w;
    *(ushort4*)(dst + (size_t)(vd + 0) * Tn + kt0 + vk) = t0;
    *(ushort4*)(dst + (size_t)(vd + 1) * Tn + kt0 + vk) = t1;
    *(ushort4*)(dst + (size_t)(vd + 2) * Tn + kt0 + vk) = t2;
    *(ushort4*)(dst + (size_t)(vd + 3) * Tn + kt0 + vk) = t3;
}

// ---------------------------------------------------------------------------
// QKV GEMM, m97-style staging. Q outputs pre-scaled by SC (exp2 domain).
// Operand-swapped MFMA (acc = C^T): each lane owns 4 consecutive d values
// -> uint2 stores (16 per wave-tile) instead of 64 scalar 2B stores.
// ---------------------------------------------------------------------------
__global__ __launch_bounds__(256) void qkv_gemm_mfma(
    const ushort* __restrict__ A, const ushort* __restrict__ Bt,
    const float* __restrict__ bias,
    ushort* __restrict__ Qo, ushort* __restrict__ Ko, ushort* __restrict__ Vo)
{
    __shared__ __align__(16) ushort As[128 * 64];
    __shared__ __align__(16) ushort Bs[128 * 64];
    const int tid = threadIdx.x;
    const int m0 = blockIdx.x * 128, n0 = blockIdx.y * 128;
    const int w = tid >> 6, lane = tid & 63, l15 = lane & 15, qd = lane >> 4;
    const int wm = (w >> 1) * 64, wn = (w & 1) * 64;
    const int lrow = lane >> 3;
    const int lchunk = (lane & 7) ^ (lrow & 7);

    const ushort* gA = A + (size_t)(m0 + w * 32 + lrow) * Cn + lchunk * 8;
    const ushort* gB = Bt + (size_t)(n0 + w * 32 + lrow) * Cn + lchunk * 8;
    ushort* lA = &As[(w * 32) * 64];
    ushort* lB = &Bs[(w * 32) * 64];

    f32x4 acc[4][4] = {};   // acc[nt][mt] = C^T tile

    for (int k0 = 0; k0 < Cn; k0 += 64) {
        __syncthreads();
#pragma unroll
        for (int t = 0; t < 4; ++t) {
            gl_lds16(gA + (size_t)t * 8 * Cn + k0, lA + t * 8 * 64);
            gl_lds16(gB + (size_t)t * 8 * Cn + k0, lB + t * 8 * 64);
        }
        __syncthreads();
#pragma unroll
        for (int ks = 0; ks < 2; ++ks) {
            const int xs = (((ks * 4 + qd) ^ (l15 & 7))) * 8;
            s16x8 af[4], bfr[4];
#pragma unroll
            for (int i = 0; i < 4; ++i) {
                af[i]  = *(const s16x8*)&As[(wm + i * 16 + l15) * 64 + xs];
                bfr[i] = *(const s16x8*)&Bs[(wn + i * 16 + l15) * 64 + xs];
            }
#pragma unroll
            for (int mt = 0; mt < 4; ++mt)
#pragma unroll
                for (int nt = 0; nt < 4; ++nt)
                    acc[nt][mt] = MFMA_BF16(bfr[nt], af[mt], acc[nt][mt]);
        }
    }

#pragma unroll
    for (int nt = 0; nt < 4; ++nt) {
        const int n_b = n0 + wn + nt * 16 + qd * 4;   // 4 consecutive d
        const float4 bv = *(const float4*)&bias[n_b];
        const int sel = n_b >> 10;
        const int h = (n_b >> 6) & 15;
        const int d = n_b & 63;
        ushort* O = (sel == 0) ? Qo : ((sel == 1) ? Ko : Vo);
        const float scl = (sel == 0) ? SC : 1.0f;
#pragma unroll
        for (int mt = 0; mt < 4; ++mt) {
            const int m_g = m0 + wm + mt * 16 + l15;
            const int b = m_g >> 11, t = m_g & 2047;
            uint2 pk;
            pk.x = pkbf((acc[nt][mt][0] + bv.x) * scl,
                        (acc[nt][mt][1] + bv.y) * scl);
            pk.y = pkbf((acc[nt][mt][2] + bv.z) * scl,
                        (acc[nt][mt][3] + bv.w) * scl);
            *(uint2*)&O[(((size_t)(b * Hn + h) * Tn + t) << 6) + d] = pk;
        }
    }
}

// ---------------------------------------------------------------------------
// MFMA flash attention. Round-1 uniform schedule (halves qt=bx and 31-bx,
// 33 tile-iters per block) + occupancy fix:
//  - V^T fragments read DIRECTLY from global (L2-resident: the 16 y-blocks
//    of one bh share an XCD since 64 blocks per y-row => block%8 = bh%8).
//    A-operand layout = 16B contiguous row slice -> no staging, no swizzle.
//  - LDS = K double-buffer (16KB) + Ps (8KB) = 24KB -> 5 blocks/CU.
// ---------------------------------------------------------------------------
__global__ __launch_bounds__(256, 5) void attn_mfma(
    const ushort* __restrict__ Q, const ushort* __restrict__ K,
    const ushort* __restrict__ Vt, ushort* __restrict__ Y)
{
    __shared__ __align__(16) ushort Ks[2][64 * 64];
    __shared__ __align__(16) ushort Ps[64 * 64];

    const int tid = threadIdx.x;
    const int bh = blockIdx.x, bx = blockIdx.y;
    const int w = tid >> 6, lane = tid & 63, l15 = lane & 15, qd = lane >> 4;
    const size_t base = (size_t)bh * Tn * Dn;
    const int lrow = lane >> 3;                   // 0..7
    const int lchunk = (lane & 7) ^ (lrow & 7);   // source-side swizzle (K DMA)
    const int q_l = w * 16 + l15;
    const int frow = q_l * 64;
    const int fx0 = ((0 * 4 + qd) ^ (l15 & 7)) * 8;
    const int fx1 = ((1 * 4 + qd) ^ (l15 & 7)) * 8;
    const int b = bh >> 4, h = bh & 15;

    // K staging source: wave w stages rows w*16 .. w*16+15 of each tile
    const ushort* Kg = K + base + (size_t)(w * 16 + lrow) * Dn + lchunk * 8;
    // V^T direct-from-global row pointers: lane reads d = dt*16+l15,
    // keys kt*64 + batch*32 + qd*8 (16B contiguous, MFMA A-layout)
    const ushort* Vg = Vt + base + (size_t)l15 * Tn + qd * 8;
    // Q fragments direct from global
    const ushort* Qp = Q + base + (size_t)l15 * Dn + qd * 8;

#pragma unroll
    for (int half = 0; half < 2; ++half) {
        const int qt = half ? (31 - bx) : bx;

        const ushort* qrow = Qp + (size_t)(qt * 64 + w * 16) * Dn;
        s16x8 qf0 = *(const s16x8*)(qrow);
        s16x8 qf1 = *(const s16x8*)(qrow + 32);

        __syncthreads();   // previous half's LDS reads complete
        // issue K DMA for tile 0 -> buffer 0
#pragma unroll
        for (int t = 0; t < 2; ++t)
            gl_lds16(Kg + (size_t)(t * 8) * Dn, &Ks[0][(w * 16 + t * 8) * 64]);

        float m_run = -1e30f, l_run = 0.f;   // l_run: per-lane partial sum
        f32x4 o[4] = {};   // O^T[d=dt*16+qd*4+r][q=l15]

        for (int kt = 0; kt <= qt; ++kt) {
            const int buf = kt & 1;
            __syncthreads();   // drains own vmcnt -> K tile kt ready
            if (kt < qt) {     // issue K DMA for kt+1 (overlaps compute)
#pragma unroll
                for (int t = 0; t < 2; ++t)
                    gl_lds16(Kg + (size_t)((kt + 1) * 64 + t * 8) * Dn,
                             &Ks[buf ^ 1][(w * 16 + t * 8) * 64]);
            }

            // V batch-0 fragments: issue early, consumed ~400cyc later in PV
            s16x8 vf0[4];
#pragma unroll
            for (int dt = 0; dt < 4; ++dt)
                vf0[dt] = *(const s16x8*)(Vg + (size_t)(dt * 16) * Tn + kt * 64);

            // S^T = K·Q^T (exp2 domain via pre-scaled Q)
            f32x4 s[4] = {};
#pragma unroll
            for (int nt = 0; nt < 4; ++nt) {
                s16x8 kf = *(const s16x8*)&Ks[buf][(nt * 16 + l15) * 64 + fx0];
                s[nt] = MFMA_BF16(kf, qf0, s[nt]);
            }
#pragma unroll
            for (int nt = 0; nt < 4; ++nt) {
                s16x8 kf = *(const s16x8*)&Ks[buf][(nt * 16 + l15) * 64 + fx1];
                s[nt] = MFMA_BF16(kf, qf1, s[nt]);
            }

            if (kt == qt) {
#pragma unroll
                for (int nt = 0; nt < 4; ++nt)
#pragma unroll
                    for (int r = 0; r < 4; ++r)
                        if (nt * 16 + qd * 4 + r > q_l) s[nt][r] = -1e30f;
            }

            // per-query max: depth-4 tree (fuses to v_max3) + 2 shuffles
            float a0 = fmaxf(fmaxf(s[0][0], s[0][1]), fmaxf(s[0][2], s[0][3]));
            float a1 = fmaxf(fmaxf(s[1][0], s[1][1]), fmaxf(s[1][2], s[1][3]));
            float a2 = fmaxf(fmaxf(s[2][0], s[2][1]), fmaxf(s[2][2], s[2][3]));
            float a3 = fmaxf(fmaxf(s[3][0], s[3][1]), fmaxf(s[3][2], s[3][3]));
            float mx = fmaxf(fmaxf(a0, a1), fmaxf(a2, a3));
            mx = fmaxf(mx, __shfl_xor(mx, 16));
            mx = fmaxf(mx, __shfl_xor(mx, 32));

            // V batch-1 fragments: issue here; covered by exp+pack+PV batch 0
            s16x8 vf1[4];
#pragma unroll
            for (int dt = 0; dt < 4; ++dt)
                vf1[dt] = *(const s16x8*)(Vg + (size_t)(dt * 16) * Tn +
                                          kt * 64 + 32);

            // defer-max: only rescale when the max grew by > 8 (2^8 bound)
            if (!__all(mx <= m_run + 8.f)) {
                float m_new = fmaxf(m_run, mx);
                float alpha = exp2f(m_run - m_new);
                m_run = m_new;
                l_run *= alpha;
                f32x2 aa = {alpha, alpha};
#pragma unroll
                for (int dt = 0; dt < 4; ++dt) {
                    o[dt].lo = pk_mul(o[dt].lo, aa);
                    o[dt].hi = pk_mul(o[dt].hi, aa);
                }
            }

            // p = exp2(s - m_run); packed subtract / packed l-accum
            const f32x2 negm = {-m_run, -m_run};
            f32x2 lac0 = {0.f, 0.f}, lac1 = {0.f, 0.f};
#pragma unroll
            for (int nt = 0; nt < 4; ++nt) {
                s[nt].lo = pk_add(s[nt].lo, negm);
                s[nt].hi = pk_add(s[nt].hi, negm);
                s[nt][0] = exp2f(s[nt][0]);
                s[nt][1] = exp2f(s[nt][1]);
                s[nt][2] = exp2f(s[nt][2]);
                s[nt][3] = exp2f(s[nt][3]);
                lac0 = pk_add(lac0, s[nt].lo);
                lac1 = pk_add(lac1, s[nt].hi);
            }
            lac0 = pk_add(lac0, lac1);
            l_run += lac0[0] + lac0[1];

            // P^T -> wave-private LDS rows (packed bf16 pairs)
#pragma unroll
            for (int nt = 0; nt < 4; ++nt) {
                uint2 pk;
                pk.x = pkbf(s[nt][0], s[nt][1]);
                pk.y = pkbf(s[nt][2], s[nt][3]);
                const int pc = 2 * nt + (qd >> 1), po = (qd & 1) * 4;
                *(uint2*)&Ps[frow + ((pc ^ (l15 & 7)) * 8) + po] = pk;
            }

            // O^T += V^T · P^T  (P via same-wave LDS round trip; V from regs)
            {
                s16x8 pb = *(const s16x8*)&Ps[frow + fx0];
#pragma unroll
                for (int dt = 0; dt < 4; ++dt)
                    o[dt] = MFMA_BF16(vf0[dt], pb, o[dt]);
                pb = *(const s16x8*)&Ps[frow + fx1];
#pragma unroll
                for (int dt = 0; dt < 4; ++dt)
                    o[dt] = MFMA_BF16(vf1[dt], pb, o[dt]);
            }
        }

        // epilogue: reduce partial l across the 4-lane query group, then
        // O^T[d][q=l15] -> Y[b, t=q_global, h*64+d]
        float lt = l_run;
        lt += __shfl_xor(lt, 16);
        lt += __shfl_xor(lt, 32);
        const float inv = 1.f / lt;
        const int t_g = qt * 64 + w * 16 + l15;
        ushort* yp = Y + ((size_t)(b * Tn + t_g)) * Cn + h * Dn + qd * 4;
#pragma unroll
        for (int dt = 0; dt < 4; ++dt) {
            uint2 pk;
            pk.x = pkbf(o[dt][0] * inv, o[dt][1] * inv);
            pk.y = pkbf(o[dt][2] * inv, o[dt][3] * inv);
            *(uint2*)(yp + dt * 16) = pk;
        }
    }
}

// ---------------------------------------------------------------------------
// Proj GEMM: Y [8192][1024] bf16, Wt [1024][1024] bf16 -> out fp32
// ---------------------------------------------------------------------------
__global__ __launch_bounds__(256) void proj_gemm_mfma(
    const ushort* __restrict__ A, const ushort* __restrict__ Bt,
    const float* __restrict__ bias, float* __restrict__ out)
{
    __shared__ __align__(16) ushort As[128 * 64];
    __shared__ __align__(16) ushort Bs[128 * 64];
    const int tid = threadIdx.x;
    const int m0 = blockIdx.x * 128, n0 = blockIdx.y * 128;
    const int w = tid >> 6, lane = tid & 63, l15 = lane & 15, qd = lane >> 4;
    const int wm = (w >> 1) * 64, wn = (w & 1) * 64;
    const int lrow = lane >> 3;
    const int lchunk = (lane & 7) ^ (lrow & 7);

    const ushort* gA = A + (size_t)(m0 + w * 32 + lrow) * Cn + lchunk * 8;
    const ushort* gB = Bt + (size_t)(n0 + w * 32 + lrow) * Cn + lchunk * 8;
    ushort* lA = &As[(w * 32) * 64];
    ushort* lB = &Bs[(w * 32) * 64];

    f32x4 acc[4][4] = {};

    for (int k0 = 0; k0 < Cn; k0 += 64) {
        __syncthreads();
#pragma unroll
        for (int t = 0; t < 4; ++t) {
            gl_lds16(gA + (size_t)t * 8 * Cn + k0, lA + t * 8 * 64);
            gl_lds16(gB + (size_t)t * 8 * Cn + k0, lB + t * 8 * 64);
        }
        __syncthreads();
#pragma unroll
        for (int ks = 0; ks < 2; ++ks) {
            const int xs = (((ks * 4 + qd) ^ (l15 & 7))) * 8;
            s16x8 af[4], bfr[4];
#pragma unroll
            for (int i = 0; i < 4; ++i) {
                af[i]  = *(const s16x8*)&As[(wm + i * 16 + l15) * 64 + xs];
                bfr[i] = *(const s16x8*)&Bs[(wn + i * 16 + l15) * 64 + xs];
            }
#pragma unroll
            for (int mt = 0; mt < 4; ++mt)
#pragma unroll
                for (int nt = 0; nt < 4; ++nt)
                    acc[mt][nt] = MFMA_BF16(af[mt], bfr[nt], acc[mt][nt]);
        }
    }

#pragma unroll
    for (int nt = 0; nt < 4; ++nt) {
        int n_g = n0 + wn + nt * 16 + l15;
        float bv = bias[n_g];
#pragma unroll
        for (int mt = 0; mt < 4; ++mt) {
#pragma unroll
            for (int r = 0; r < 4; ++r) {
                int m_g = m0 + wm + mt * 16 + qd * 4 + r;
                out[(size_t)m_g * Cn + n_g] = acc[mt][nt][r] + bv;
            }
        }
    }
}

// ---------------------------------------------------------------------------
extern "C" void kernel_launch(void* const* d_in, const int* in_sizes, int n_in,
                              void* d_out, int out_size, void* d_ws, size_t ws_size,
                              hipStream_t stream) {
    const float* x      = (const float*)d_in[0];
    const float* W_attn = (const float*)d_in[1];
    const float* b_attn = (const float*)d_in[2];
    const float* W_proj = (const float*)d_in[3];
    const float* b_proj = (const float*)d_in[4];
    float* out = (float*)d_out;

    // ws: Q, K, V [B,H,T,D] bf16, Y [B,T,C] bf16
    constexpr size_t PER = (size_t)Mn * Cn;  // 8388608 elems
    ushort* Qb = (ushort*)d_ws;
    ushort* Kb = Qb + PER;
    ushort* Vb = Kb + PER;
    ushort* Yb = Vb + PER;

    // d_out as scratch (33.5 MB):
    //   phase 1 (pre-GEMM): WtA [3072][1024] bf16 (6.3MB) + x_bf (16.8MB)
    //   phase 2 (post-GEMM, pre-proj): Vtb [bh][d][t] bf16 (16.8MB) at offset 0
    ushort* WtA  = (ushort*)d_out;
    ushort* x_bf = WtA + (size_t)Nqkv * Cn;
    ushort* Vtb  = (ushort*)d_out;     // overwrites WtA/x_bf after qkv_gemm
    ushort* WtP  = Qb;                 // reuses Q buffer (dead after attention)

    conv_bf16_kernel<<<1024, 256, 0, stream>>>(x, x_bf, (int)(PER / 4));
    transpose_cvt_kernel<<<dim3(Nqkv / 64, Cn / 64), 256, 0, stream>>>(
        W_attn, WtA, Cn, Nqkv);
    qkv_gemm_mfma<<<dim3(Mn / 128, Nqkv / 128), 256, 0, stream>>>(
        x_bf, WtA, b_attn, Qb, Kb, Vb);
    vt_transpose_kernel<<<dim3(Bn * Hn, Tn / 64), 256, 0, stream>>>(Vb, Vtb);
    attn_mfma<<<dim3(Bn * Hn, 16), 256, 0, stream>>>(Qb, Kb, Vtb, Yb);
    transpose_cvt_kernel<<<dim3(Cn / 64, Cn / 64), 256, 0, stream>>>(
        W_proj, WtP, Cn, Cn);
    proj_gemm_mfma<<<dim3(Mn / 128, Cn / 128), 256, 0, stream>>>(
        Yb, WtP, b_proj, out);
}

// Round 5
// 273.385 us; speedup vs baseline: 1.3021x; 1.3021x over previous
//
#include <hip/hip_runtime.h>
#include <hip/hip_bf16.h>

typedef short s16x8 __attribute__((ext_vector_type(8)));
typedef float f32x4 __attribute__((ext_vector_type(4)));
typedef float f32x2 __attribute__((ext_vector_type(2)));

#define MFMA_BF16(A, B, C) __builtin_amdgcn_mfma_f32_16x16x32_bf16(A, B, C, 0, 0, 0)

constexpr int Bn = 4, Tn = 2048, Cn = 1024, Hn = 16, Dn = 64;
constexpr int Mn = Bn * Tn;      // 8192
constexpr int Nqkv = 3 * Cn;     // 3072
constexpr float SC = 0.125f * 1.44269504089f;  // 1/sqrt(D) * log2(e)

__device__ __forceinline__ ushort f2bfu(float f) {
    __hip_bfloat16 h = __float2bfloat16(f);
    return *reinterpret_cast<ushort*>(&h);
}
__device__ __forceinline__ uint pkbf(float a, float b) {
    __hip_bfloat162 h = __float22bfloat162_rn(make_float2(a, b));
    return *reinterpret_cast<uint*>(&h);
}

// packed fp32 VALU (full-rate on CDNA4)
__device__ __forceinline__ f32x2 pk_add(f32x2 a, f32x2 b) {
    f32x2 d; asm("v_pk_add_f32 %0, %1, %2" : "=v"(d) : "v"(a), "v"(b)); return d;
}
__device__ __forceinline__ f32x2 pk_mul(f32x2 a, f32x2 b) {
    f32x2 d; asm("v_pk_mul_f32 %0, %1, %2" : "=v"(d) : "v"(a), "v"(b)); return d;
}

// async global->LDS, 16B per lane; LDS dest = wave-uniform base + lane*16.
__device__ __forceinline__ void gl_lds16(const void* g, void* l) {
    __builtin_amdgcn_global_load_lds(
        (const __attribute__((address_space(1))) void*)(uintptr_t)g,
        (__attribute__((address_space(3))) void*)(uint32_t)(uintptr_t)l,
        16, 0, 0);
}

// ---------------------------------------------------------------------------
// fp32 -> bf16 elementwise (x)
// ---------------------------------------------------------------------------
__global__ __launch_bounds__(256) void conv_bf16_kernel(
    const float* __restrict__ src, ushort* __restrict__ dst, int n4)
{
    int i = blockIdx.x * blockDim.x + threadIdx.x;
    int stride = gridDim.x * blockDim.x;
    for (; i < n4; i += stride) {
        float4 v = ((const float4*)src)[i];
        ushort4 o;
        o.x = f2bfu(v.x); o.y = f2bfu(v.y); o.z = f2bfu(v.z); o.w = f2bfu(v.w);
        ((ushort4*)dst)[i] = o;
    }
}

// ---------------------------------------------------------------------------
// W [K][N] fp32  ->  Wt [N][K] bf16   (64x64 tiles via LDS)
// ---------------------------------------------------------------------------
__global__ __launch_bounds__(256) void transpose_cvt_kernel(
    const float* __restrict__ W, ushort* __restrict__ Wt, int K, int N)
{
    __shared__ __align__(16) float Ls[64][68];
    const int t = threadIdx.x;
    const int n0 = blockIdx.x * 64, k0 = blockIdx.y * 64;
#pragma unroll
    for (int p = 0; p < 4; ++p) {
        int r = (t >> 4) + p * 16;
        int c = (t & 15) * 4;
        *(float4*)&Ls[r][c] = *(const float4*)&W[(size_t)(k0 + r) * N + n0 + c];
    }
    __syncthreads();
    const int n = t >> 2;
    const int ks = (t & 3) * 16;
    union { ushort s[16]; uint4 u[2]; } tmp;
#pragma unroll
    for (int j = 0; j < 16; ++j) tmp.s[j] = f2bfu(Ls[ks + j][n]);
    uint4* dp = (uint4*)&Wt[(size_t)(n0 + n) * K + k0 + ks];
    dp[0] = tmp.u[0];
    dp[1] = tmp.u[1];
}

// ---------------------------------------------------------------------------
// V [bh][t][d] bf16 -> Vt [bh][d][t] bf16 (4x4 in-register transpose)
// ---------------------------------------------------------------------------
__global__ __launch_bounds__(256) void vt_transpose_kernel(
    const ushort* __restrict__ V, ushort* __restrict__ Vt)
{
    const int tid = threadIdx.x;
    const int bh = blockIdx.x;
    const int kt0 = blockIdx.y * 64;
    const ushort* src = V + (size_t)bh * Tn * Dn;
    ushort* dst = Vt + (size_t)bh * Dn * Tn;
    const int vk = (tid & 15) * 4, vd = (tid >> 4) * 4;
    const ushort* g = src + (size_t)(kt0 + vk) * Dn + vd;
    ushort4 v0 = *(const ushort4*)(g);
    ushort4 v1 = *(const ushort4*)(g + Dn);
    ushort4 v2 = *(const ushort4*)(g + 2 * Dn);
    ushort4 v3 = *(const ushort4*)(g + 3 * Dn);
    ushort4 t0, t1, t2, t3;
    t0.x = v0.x; t0.y = v1.x; t0.z = v2.x; t0.w = v3.x;
    t1.x = v0.y; t1.y = v1.y; t1.z = v2.y; t1.w = v3.y;
    t2.x = v0.z; t2.y = v1.z; t2.z = v2.z; t2.w = v3.z;
    t3.x = v0.w; t3.y = v1.w; t3.z = v2.w; t3.w = v3.w;
    *(ushort4*)(dst + (size_t)(vd + 0) * Tn + kt0 + vk) = t0;
    *(ushort4*)(dst + (size_t)(vd + 1) * Tn + kt0 + vk) = t1;
    *(ushort4*)(dst + (size_t)(vd + 2) * Tn + kt0 + vk) = t2;
    *(ushort4*)(dst + (size_t)(vd + 3) * Tn + kt0 + vk) = t3;
}

// ---------------------------------------------------------------------------
// QKV GEMM, m97-style staging. Q outputs pre-scaled by SC (exp2 domain).
// Operand-swapped MFMA (acc = C^T): each lane owns 4 consecutive d values
// -> uint2 stores (16 per wave-tile) instead of 64 scalar 2B stores.
// ---------------------------------------------------------------------------
__global__ __launch_bounds__(256) void qkv_gemm_mfma(
    const ushort* __restrict__ A, const ushort* __restrict__ Bt,
    const float* __restrict__ bias,
    ushort* __restrict__ Qo, ushort* __restrict__ Ko, ushort* __restrict__ Vo)
{
    __shared__ __align__(16) ushort As[128 * 64];
    __shared__ __align__(16) ushort Bs[128 * 64];
    const int tid = threadIdx.x;
    const int m0 = blockIdx.x * 128, n0 = blockIdx.y * 128;
    const int w = tid >> 6, lane = tid & 63, l15 = lane & 15, qd = lane >> 4;
    const int wm = (w >> 1) * 64, wn = (w & 1) * 64;
    const int lrow = lane >> 3;
    const int lchunk = (lane & 7) ^ (lrow & 7);

    const ushort* gA = A + (size_t)(m0 + w * 32 + lrow) * Cn + lchunk * 8;
    const ushort* gB = Bt + (size_t)(n0 + w * 32 + lrow) * Cn + lchunk * 8;
    ushort* lA = &As[(w * 32) * 64];
    ushort* lB = &Bs[(w * 32) * 64];

    f32x4 acc[4][4] = {};   // acc[nt][mt] = C^T tile

    for (int k0 = 0; k0 < Cn; k0 += 64) {
        __syncthreads();
#pragma unroll
        for (int t = 0; t < 4; ++t) {
            gl_lds16(gA + (size_t)t * 8 * Cn + k0, lA + t * 8 * 64);
            gl_lds16(gB + (size_t)t * 8 * Cn + k0, lB + t * 8 * 64);
        }
        __syncthreads();
#pragma unroll
        for (int ks = 0; ks < 2; ++ks) {
            const int xs = (((ks * 4 + qd) ^ (l15 & 7))) * 8;
            s16x8 af[4], bfr[4];
#pragma unroll
            for (int i = 0; i < 4; ++i) {
                af[i]  = *(const s16x8*)&As[(wm + i * 16 + l15) * 64 + xs];
                bfr[i] = *(const s16x8*)&Bs[(wn + i * 16 + l15) * 64 + xs];
            }
#pragma unroll
            for (int mt = 0; mt < 4; ++mt)
#pragma unroll
                for (int nt = 0; nt < 4; ++nt)
                    acc[nt][mt] = MFMA_BF16(bfr[nt], af[mt], acc[nt][mt]);
        }
    }

#pragma unroll
    for (int nt = 0; nt < 4; ++nt) {
        const int n_b = n0 + wn + nt * 16 + qd * 4;   // 4 consecutive d
        const float4 bv = *(const float4*)&bias[n_b];
        const int sel = n_b >> 10;
        const int h = (n_b >> 6) & 15;
        const int d = n_b & 63;
        ushort* O = (sel == 0) ? Qo : ((sel == 1) ? Ko : Vo);
        const float scl = (sel == 0) ? SC : 1.0f;
#pragma unroll
        for (int mt = 0; mt < 4; ++mt) {
            const int m_g = m0 + wm + mt * 16 + l15;
            const int b = m_g >> 11, t = m_g & 2047;
            uint2 pk;
            pk.x = pkbf((acc[nt][mt][0] + bv.x) * scl,
                        (acc[nt][mt][1] + bv.y) * scl);
            pk.y = pkbf((acc[nt][mt][2] + bv.z) * scl,
                        (acc[nt][mt][3] + bv.w) * scl);
            *(uint2*)&O[(((size_t)(b * Hn + h) * Tn + t) << 6) + d] = pk;
        }
    }
}

// ---------------------------------------------------------------------------
// MFMA flash attention (r1 structure, proven 90.6us), async-DMA pipelined:
//  - K and Vt tiles staged cooperatively via global_load_lds(16B), double-
//    buffered; tile kt+1's DMA issued right after the barrier publishing kt.
//  - swizzle realized by permuting SOURCE addresses (DMA dest is lane-linear)
//  - transposed-S formulation, exp2 softmax, wave-private P^T LDS round trip
//  - VALU-diet softmax: defer-max, packed f32 ops, deferred l reduction
//  - T5: s_setprio(1) around MFMA clusters (blocks on a CU are at different
//    kt phases -> scheduler can favor MFMA-entering waves; m191 regime)
// ---------------------------------------------------------------------------
__global__ __launch_bounds__(256, 4) void attn_mfma(
    const ushort* __restrict__ Q, const ushort* __restrict__ K,
    const ushort* __restrict__ Vt, ushort* __restrict__ Y)
{
    __shared__ __align__(16) ushort Ks[2][64 * 64];
    __shared__ __align__(16) ushort Vs[2][64 * 64];
    __shared__ __align__(16) ushort Ps[64 * 64];

    const int tid = threadIdx.x;
    const int bh = blockIdx.x, bx = blockIdx.y;
    const int w = tid >> 6, lane = tid & 63, l15 = lane & 15, qd = lane >> 4;
    const size_t base = (size_t)bh * Tn * Dn;
    const int lrow = lane >> 3;                   // 0..7
    const int lchunk = (lane & 7) ^ (lrow & 7);   // source-side swizzle
    const int q_l = w * 16 + l15;
    const int frow = q_l * 64;
    const int fx0 = ((0 * 4 + qd) ^ (l15 & 7)) * 8;
    const int fx1 = ((1 * 4 + qd) ^ (l15 & 7)) * 8;
    const int b = bh >> 4, h = bh & 15;

    // staging sources: wave w stages rows w*16 .. w*16+15 of each tile
    const ushort* Kg = K + base + (size_t)(w * 16 + lrow) * Dn + lchunk * 8;
    const ushort* Vg = Vt + base + (size_t)(w * 16 + lrow) * Tn + lchunk * 8;
    // Q fragments direct from global
    const ushort* Qp = Q + base + (size_t)l15 * Dn + qd * 8;

#pragma unroll
    for (int half = 0; half < 2; ++half) {
        const int qt = half ? (31 - bx) : bx;

        const ushort* qrow = Qp + (size_t)(qt * 64 + w * 16) * Dn;
        s16x8 qf0 = *(const s16x8*)(qrow);
        s16x8 qf1 = *(const s16x8*)(qrow + 32);

        __syncthreads();   // previous half's LDS reads complete
        // issue DMA for tile 0 -> buffer 0
#pragma unroll
        for (int t = 0; t < 2; ++t) {
            gl_lds16(Kg + (size_t)(t * 8) * Dn, &Ks[0][(w * 16 + t * 8) * 64]);
            gl_lds16(Vg + (size_t)(t * 8) * Tn, &Vs[0][(w * 16 + t * 8) * 64]);
        }

        float m_run = -1e30f, l_run = 0.f;   // l_run: per-lane partial sum
        f32x4 o[4] = {};   // O^T[d=dt*16+qd*4+r][q=l15]

        for (int kt = 0; kt <= qt; ++kt) {
            const int buf = kt & 1;
            __syncthreads();   // drains own vmcnt -> tile kt ready; buf^1 free
            if (kt < qt) {     // issue DMA for kt+1 -> buf^1 (overlaps compute)
#pragma unroll
                for (int t = 0; t < 2; ++t) {
                    gl_lds16(Kg + (size_t)((kt + 1) * 64 + t * 8) * Dn,
                             &Ks[buf ^ 1][(w * 16 + t * 8) * 64]);
                    gl_lds16(Vg + (size_t)(t * 8) * Tn + (kt + 1) * 64,
                             &Vs[buf ^ 1][(w * 16 + t * 8) * 64]);
                }
            }

            // S^T = K·Q^T (exp2 domain via pre-scaled Q)
            f32x4 s[4] = {};
            __builtin_amdgcn_s_setprio(1);
#pragma unroll
            for (int nt = 0; nt < 4; ++nt) {
                s16x8 kf = *(const s16x8*)&Ks[buf][(nt * 16 + l15) * 64 + fx0];
                s[nt] = MFMA_BF16(kf, qf0, s[nt]);
            }
#pragma unroll
            for (int nt = 0; nt < 4; ++nt) {
                s16x8 kf = *(const s16x8*)&Ks[buf][(nt * 16 + l15) * 64 + fx1];
                s[nt] = MFMA_BF16(kf, qf1, s[nt]);
            }
            __builtin_amdgcn_s_setprio(0);

            if (kt == qt) {
#pragma unroll
                for (int nt = 0; nt < 4; ++nt)
#pragma unroll
                    for (int r = 0; r < 4; ++r)
                        if (nt * 16 + qd * 4 + r > q_l) s[nt][r] = -1e30f;
            }

            // per-query max: depth-4 tree (fuses to v_max3) + 2 shuffles
            float a0 = fmaxf(fmaxf(s[0][0], s[0][1]), fmaxf(s[0][2], s[0][3]));
            float a1 = fmaxf(fmaxf(s[1][0], s[1][1]), fmaxf(s[1][2], s[1][3]));
            float a2 = fmaxf(fmaxf(s[2][0], s[2][1]), fmaxf(s[2][2], s[2][3]));
            float a3 = fmaxf(fmaxf(s[3][0], s[3][1]), fmaxf(s[3][2], s[3][3]));
            float mx = fmaxf(fmaxf(a0, a1), fmaxf(a2, a3));
            mx = fmaxf(mx, __shfl_xor(mx, 16));
            mx = fmaxf(mx, __shfl_xor(mx, 32));

            // defer-max: only rescale when the max grew by > 8 (2^8 bound)
            if (!__all(mx <= m_run + 8.f)) {
                float m_new = fmaxf(m_run, mx);
                float alpha = exp2f(m_run - m_new);
                m_run = m_new;
                l_run *= alpha;
                f32x2 aa = {alpha, alpha};
#pragma unroll
                for (int dt = 0; dt < 4; ++dt) {
                    o[dt].lo = pk_mul(o[dt].lo, aa);
                    o[dt].hi = pk_mul(o[dt].hi, aa);
                }
            }

            // p = exp2(s - m_run); packed subtract / packed l-accum
            const f32x2 negm = {-m_run, -m_run};
            f32x2 lac0 = {0.f, 0.f}, lac1 = {0.f, 0.f};
#pragma unroll
            for (int nt = 0; nt < 4; ++nt) {
                s[nt].lo = pk_add(s[nt].lo, negm);
                s[nt].hi = pk_add(s[nt].hi, negm);
                s[nt][0] = exp2f(s[nt][0]);
                s[nt][1] = exp2f(s[nt][1]);
                s[nt][2] = exp2f(s[nt][2]);
                s[nt][3] = exp2f(s[nt][3]);
                lac0 = pk_add(lac0, s[nt].lo);
                lac1 = pk_add(lac1, s[nt].hi);
            }
            lac0 = pk_add(lac0, lac1);
            l_run += lac0[0] + lac0[1];

            // P^T -> wave-private LDS rows (packed bf16 pairs)
#pragma unroll
            for (int nt = 0; nt < 4; ++nt) {
                uint2 pk;
                pk.x = pkbf(s[nt][0], s[nt][1]);
                pk.y = pkbf(s[nt][2], s[nt][3]);
                const int pc = 2 * nt + (qd >> 1), po = (qd & 1) * 4;
                *(uint2*)&Ps[frow + ((pc ^ (l15 & 7)) * 8) + po] = pk;
            }

            // O^T += V^T · P^T  (same-wave LDS round trip; no barrier)
            {
                s16x8 pb = *(const s16x8*)&Ps[frow + fx0];
                __builtin_amdgcn_s_setprio(1);
#pragma unroll
                for (int dt = 0; dt < 4; ++dt) {
                    s16x8 vf = *(const s16x8*)&Vs[buf][(dt * 16 + l15) * 64 + fx0];
                    o[dt] = MFMA_BF16(vf, pb, o[dt]);
                }
                pb = *(const s16x8*)&Ps[frow + fx1];
#pragma unroll
                for (int dt = 0; dt < 4; ++dt) {
                    s16x8 vf = *(const s16x8*)&Vs[buf][(dt * 16 + l15) * 64 + fx1];
                    o[dt] = MFMA_BF16(vf, pb, o[dt]);
                }
                __builtin_amdgcn_s_setprio(0);
            }
        }

        // epilogue: reduce partial l across the 4-lane query group, then
        // O^T[d][q=l15] -> Y[b, t=q_global, h*64+d]
        float lt = l_run;
        lt += __shfl_xor(lt, 16);
        lt += __shfl_xor(lt, 32);
        const float inv = 1.f / lt;
        const int t_g = qt * 64 + w * 16 + l15;
        ushort* yp = Y + ((size_t)(b * Tn + t_g)) * Cn + h * Dn + qd * 4;
#pragma unroll
        for (int dt = 0; dt < 4; ++dt) {
            uint2 pk;
            pk.x = pkbf(o[dt][0] * inv, o[dt][1] * inv);
            pk.y = pkbf(o[dt][2] * inv, o[dt][3] * inv);
            *(uint2*)(yp + dt * 16) = pk;
        }
    }
}

// ---------------------------------------------------------------------------
// Proj GEMM: Y [8192][1024] bf16, Wt [1024][1024] bf16 -> out fp32
// ---------------------------------------------------------------------------
__global__ __launch_bounds__(256) void proj_gemm_mfma(
    const ushort* __restrict__ A, const ushort* __restrict__ Bt,
    const float* __restrict__ bias, float* __restrict__ out)
{
    __shared__ __align__(16) ushort As[128 * 64];
    __shared__ __align__(16) ushort Bs[128 * 64];
    const int tid = threadIdx.x;
    const int m0 = blockIdx.x * 128, n0 = blockIdx.y * 128;
    const int w = tid >> 6, lane = tid & 63, l15 = lane & 15, qd = lane >> 4;
    const int wm = (w >> 1) * 64, wn = (w & 1) * 64;
    const int lrow = lane >> 3;
    const int lchunk = (lane & 7) ^ (lrow & 7);

    const ushort* gA = A + (size_t)(m0 + w * 32 + lrow) * Cn + lchunk * 8;
    const ushort* gB = Bt + (size_t)(n0 + w * 32 + lrow) * Cn + lchunk * 8;
    ushort* lA = &As[(w * 32) * 64];
    ushort* lB = &Bs[(w * 32) * 64];

    f32x4 acc[4][4] = {};

    for (int k0 = 0; k0 < Cn; k0 += 64) {
        __syncthreads();
#pragma unroll
        for (int t = 0; t < 4; ++t) {
            gl_lds16(gA + (size_t)t * 8 * Cn + k0, lA + t * 8 * 64);
            gl_lds16(gB + (size_t)t * 8 * Cn + k0, lB + t * 8 * 64);
        }
        __syncthreads();
#pragma unroll
        for (int ks = 0; ks < 2; ++ks) {
            const int xs = (((ks * 4 + qd) ^ (l15 & 7))) * 8;
            s16x8 af[4], bfr[4];
#pragma unroll
            for (int i = 0; i < 4; ++i) {
                af[i]  = *(const s16x8*)&As[(wm + i * 16 + l15) * 64 + xs];
                bfr[i] = *(const s16x8*)&Bs[(wn + i * 16 + l15) * 64 + xs];
            }
#pragma unroll
            for (int mt = 0; mt < 4; ++mt)
#pragma unroll
                for (int nt = 0; nt < 4; ++nt)
                    acc[mt][nt] = MFMA_BF16(af[mt], bfr[nt], acc[mt][nt]);
        }
    }

#pragma unroll
    for (int nt = 0; nt < 4; ++nt) {
        int n_g = n0 + wn + nt * 16 + l15;
        float bv = bias[n_g];
#pragma unroll
        for (int mt = 0; mt < 4; ++mt) {
#pragma unroll
            for (int r = 0; r < 4; ++r) {
                int m_g = m0 + wm + mt * 16 + qd * 4 + r;
                out[(size_t)m_g * Cn + n_g] = acc[mt][nt][r] + bv;
            }
        }
    }
}

// ---------------------------------------------------------------------------
extern "C" void kernel_launch(void* const* d_in, const int* in_sizes, int n_in,
                              void* d_out, int out_size, void* d_ws, size_t ws_size,
                              hipStream_t stream) {
    const float* x      = (const float*)d_in[0];
    const float* W_attn = (const float*)d_in[1];
    const float* b_attn = (const float*)d_in[2];
    const float* W_proj = (const float*)d_in[3];
    const float* b_proj = (const float*)d_in[4];
    float* out = (float*)d_out;

    // ws: Q, K, V [B,H,T,D] bf16, Y [B,T,C] bf16
    constexpr size_t PER = (size_t)Mn * Cn;  // 8388608 elems
    ushort* Qb = (ushort*)d_ws;
    ushort* Kb = Qb + PER;
    ushort* Vb = Kb + PER;
    ushort* Yb = Vb + PER;

    // d_out as scratch (33.5 MB):
    //   phase 1 (pre-GEMM): WtA [3072][1024] bf16 (6.3MB) + x_bf (16.8MB)
    //   phase 2 (post-GEMM, pre-proj): Vtb [bh][d][t] bf16 (16.8MB) at offset 0
    ushort* WtA  = (ushort*)d_out;
    ushort* x_bf = WtA + (size_t)Nqkv * Cn;
    ushort* Vtb  = (ushort*)d_out;     // overwrites WtA/x_bf after qkv_gemm
    ushort* WtP  = Qb;                 // reuses Q buffer (dead after attention)

    conv_bf16_kernel<<<1024, 256, 0, stream>>>(x, x_bf, (int)(PER / 4));
    transpose_cvt_kernel<<<dim3(Nqkv / 64, Cn / 64), 256, 0, stream>>>(
        W_attn, WtA, Cn, Nqkv);
    qkv_gemm_mfma<<<dim3(Mn / 128, Nqkv / 128), 256, 0, stream>>>(
        x_bf, WtA, b_attn, Qb, Kb, Vb);
    vt_transpose_kernel<<<dim3(Bn * Hn, Tn / 64), 256, 0, stream>>>(Vb, Vtb);
    attn_mfma<<<dim3(Bn * Hn, 16), 256, 0, stream>>>(Qb, Kb, Vtb, Yb);
    transpose_cvt_kernel<<<dim3(Cn / 64, Cn / 64), 256, 0, stream>>>(
        W_proj, WtP, Cn, Cn);
    proj_gemm_mfma<<<dim3(Mn / 128, Cn / 128), 256, 0, stream>>>(
        Yb, WtP, b_proj, out);
}

// Round 6
// 254.135 us; speedup vs baseline: 1.4007x; 1.0757x over previous
//
#include <hip/hip_runtime.h>
#include <hip/hip_bf16.h>

typedef short s16x8 __attribute__((ext_vector_type(8)));
typedef float f32x4 __attribute__((ext_vector_type(4)));
typedef float f32x2 __attribute__((ext_vector_type(2)));

#define MFMA_BF16(A, B, C) __builtin_amdgcn_mfma_f32_16x16x32_bf16(A, B, C, 0, 0, 0)

constexpr int Bn = 4, Tn = 2048, Cn = 1024, Hn = 16, Dn = 64;
constexpr int Mn = Bn * Tn;      // 8192
constexpr int Nqkv = 3 * Cn;     // 3072
constexpr float SC = 0.125f * 1.44269504089f;  // 1/sqrt(D) * log2(e)

__device__ __forceinline__ ushort f2bfu(float f) {
    __hip_bfloat16 h = __float2bfloat16(f);
    return *reinterpret_cast<ushort*>(&h);
}
__device__ __forceinline__ uint pkbf(float a, float b) {
    __hip_bfloat162 h = __float22bfloat162_rn(make_float2(a, b));
    return *reinterpret_cast<uint*>(&h);
}

// packed fp32 VALU (full-rate on CDNA4)
__device__ __forceinline__ f32x2 pk_add(f32x2 a, f32x2 b) {
    f32x2 d; asm("v_pk_add_f32 %0, %1, %2" : "=v"(d) : "v"(a), "v"(b)); return d;
}
__device__ __forceinline__ f32x2 pk_mul(f32x2 a, f32x2 b) {
    f32x2 d; asm("v_pk_mul_f32 %0, %1, %2" : "=v"(d) : "v"(a), "v"(b)); return d;
}

// async global->LDS, 16B per lane; LDS dest = wave-uniform base + lane*16.
__device__ __forceinline__ void gl_lds16(const void* g, void* l) {
    __builtin_amdgcn_global_load_lds(
        (const __attribute__((address_space(1))) void*)(uintptr_t)g,
        (__attribute__((address_space(3))) void*)(uint32_t)(uintptr_t)l,
        16, 0, 0);
}

// ---------------------------------------------------------------------------
// fp32 -> bf16 elementwise (x)
// ---------------------------------------------------------------------------
__global__ __launch_bounds__(256) void conv_bf16_kernel(
    const float* __restrict__ src, ushort* __restrict__ dst, int n4)
{
    int i = blockIdx.x * blockDim.x + threadIdx.x;
    int stride = gridDim.x * blockDim.x;
    for (; i < n4; i += stride) {
        float4 v = ((const float4*)src)[i];
        ushort4 o;
        o.x = f2bfu(v.x); o.y = f2bfu(v.y); o.z = f2bfu(v.z); o.w = f2bfu(v.w);
        ((ushort4*)dst)[i] = o;
    }
}

// ---------------------------------------------------------------------------
// W [K][N] fp32  ->  Wt [N][K] bf16   (64x64 tiles via LDS)
// ---------------------------------------------------------------------------
__global__ __launch_bounds__(256) void transpose_cvt_kernel(
    const float* __restrict__ W, ushort* __restrict__ Wt, int K, int N)
{
    __shared__ __align__(16) float Ls[64][68];
    const int t = threadIdx.x;
    const int n0 = blockIdx.x * 64, k0 = blockIdx.y * 64;
#pragma unroll
    for (int p = 0; p < 4; ++p) {
        int r = (t >> 4) + p * 16;
        int c = (t & 15) * 4;
        *(float4*)&Ls[r][c] = *(const float4*)&W[(size_t)(k0 + r) * N + n0 + c];
    }
    __syncthreads();
    const int n = t >> 2;
    const int ks = (t & 3) * 16;
    union { ushort s[16]; uint4 u[2]; } tmp;
#pragma unroll
    for (int j = 0; j < 16; ++j) tmp.s[j] = f2bfu(Ls[ks + j][n]);
    uint4* dp = (uint4*)&Wt[(size_t)(n0 + n) * K + k0 + ks];
    dp[0] = tmp.u[0];
    dp[1] = tmp.u[1];
}

// ---------------------------------------------------------------------------
// QKV GEMM, m97-style staging. Q outputs pre-scaled by SC (exp2 domain).
// Blocks are column-pure (8 y-blocks per output tensor):
//  - Q/K blocks: standard orientation, epilogue lanes l15 -> d (32B chunks)
//  - V blocks: swapped orientation (lanes l15 -> t), store DIRECTLY into
//    transposed Vt [bh][d][t] layout with t-consecutive scalars
//    -> vt_transpose kernel eliminated.
// ---------------------------------------------------------------------------
__global__ __launch_bounds__(256) void qkv_gemm_mfma(
    const ushort* __restrict__ A, const ushort* __restrict__ Bt,
    const float* __restrict__ bias,
    ushort* __restrict__ Qo, ushort* __restrict__ Ko, ushort* __restrict__ Vo)
{
    __shared__ __align__(16) ushort As[128 * 64];
    __shared__ __align__(16) ushort Bs[128 * 64];
    const int tid = threadIdx.x;
    const int m0 = blockIdx.x * 128, n0 = blockIdx.y * 128;
    const int w = tid >> 6, lane = tid & 63, l15 = lane & 15, qd = lane >> 4;
    const int wm = (w >> 1) * 64, wn = (w & 1) * 64;
    const int lrow = lane >> 3;
    const int lchunk = (lane & 7) ^ (lrow & 7);

    const ushort* gA = A + (size_t)(m0 + w * 32 + lrow) * Cn + lchunk * 8;
    const ushort* gB = Bt + (size_t)(n0 + w * 32 + lrow) * Cn + lchunk * 8;
    ushort* lA = &As[(w * 32) * 64];
    ushort* lB = &Bs[(w * 32) * 64];

    f32x4 acc[4][4] = {};
    const bool isV = (n0 >= 2 * Cn);   // block-uniform

    if (!isV) {
        // ---- Q/K path: standard orientation (r1-proven) ----
        for (int k0 = 0; k0 < Cn; k0 += 64) {
            __syncthreads();
#pragma unroll
            for (int t = 0; t < 4; ++t) {
                gl_lds16(gA + (size_t)t * 8 * Cn + k0, lA + t * 8 * 64);
                gl_lds16(gB + (size_t)t * 8 * Cn + k0, lB + t * 8 * 64);
            }
            __syncthreads();
#pragma unroll
            for (int ks = 0; ks < 2; ++ks) {
                const int xs = (((ks * 4 + qd) ^ (l15 & 7))) * 8;
                s16x8 af[4], bfr[4];
#pragma unroll
                for (int i = 0; i < 4; ++i) {
                    af[i]  = *(const s16x8*)&As[(wm + i * 16 + l15) * 64 + xs];
                    bfr[i] = *(const s16x8*)&Bs[(wn + i * 16 + l15) * 64 + xs];
                }
#pragma unroll
                for (int mt = 0; mt < 4; ++mt)
#pragma unroll
                    for (int nt = 0; nt < 4; ++nt)
                        acc[mt][nt] = MFMA_BF16(af[mt], bfr[nt], acc[mt][nt]);
            }
        }
        const int sel = n0 >> 10;               // 0=Q, 1=K (uniform)
        ushort* O = (sel == 0) ? Qo : Ko;
        const float scl = (sel == 0) ? SC : 1.0f;
#pragma unroll
        for (int nt = 0; nt < 4; ++nt) {
            const int n_g = n0 + wn + nt * 16 + l15;
            const float bv = bias[n_g];
            const int h = (n_g >> 6) & 15;
            const int d = n_g & 63;
#pragma unroll
            for (int mt = 0; mt < 4; ++mt) {
#pragma unroll
                for (int r = 0; r < 4; ++r) {
                    const int m_g = m0 + wm + mt * 16 + qd * 4 + r;
                    const int b = m_g >> 11, t = m_g & 2047;
                    O[(((size_t)(b * Hn + h) * Tn + t) << 6) + d] =
                        f2bfu((acc[mt][nt][r] + bv) * scl);
                }
            }
        }
    } else {
        // ---- V path: swapped orientation (r4-proven layout), direct Vt ----
        for (int k0 = 0; k0 < Cn; k0 += 64) {
            __syncthreads();
#pragma unroll
            for (int t = 0; t < 4; ++t) {
                gl_lds16(gA + (size_t)t * 8 * Cn + k0, lA + t * 8 * 64);
                gl_lds16(gB + (size_t)t * 8 * Cn + k0, lB + t * 8 * 64);
            }
            __syncthreads();
#pragma unroll
            for (int ks = 0; ks < 2; ++ks) {
                const int xs = (((ks * 4 + qd) ^ (l15 & 7))) * 8;
                s16x8 af[4], bfr[4];
#pragma unroll
                for (int i = 0; i < 4; ++i) {
                    af[i]  = *(const s16x8*)&As[(wm + i * 16 + l15) * 64 + xs];
                    bfr[i] = *(const s16x8*)&Bs[(wn + i * 16 + l15) * 64 + xs];
                }
#pragma unroll
                for (int mt = 0; mt < 4; ++mt)
#pragma unroll
                    for (int nt = 0; nt < 4; ++nt)
                        acc[nt][mt] = MFMA_BF16(bfr[nt], af[mt], acc[nt][mt]);
            }
        }
        // acc[nt][mt]: lane l15 -> t (m), qd*4+j -> d (n).
        // Vt [bh][d][t]: lanes give consecutive t -> 32B chunks per row.
#pragma unroll
        for (int nt = 0; nt < 4; ++nt) {
            const int n_b = n0 + wn + nt * 16 + qd * 4;   // 4 consecutive d
            const float4 bv = *(const float4*)&bias[n_b];
            const int h = (n_b >> 6) & 15;
            const int d0 = n_b & 63;
#pragma unroll
            for (int mt = 0; mt < 4; ++mt) {
                const int m_g = m0 + wm + mt * 16 + l15;
                const int b = m_g >> 11, tt = m_g & 2047;
                const size_t rowb = (size_t)(b * Hn + h) * Dn;
                Vo[(rowb + d0 + 0) * Tn + tt] = f2bfu(acc[nt][mt][0] + bv.x);
                Vo[(rowb + d0 + 1) * Tn + tt] = f2bfu(acc[nt][mt][1] + bv.y);
                Vo[(rowb + d0 + 2) * Tn + tt] = f2bfu(acc[nt][mt][2] + bv.z);
                Vo[(rowb + d0 + 3) * Tn + tt] = f2bfu(acc[nt][mt][3] + bv.w);
            }
        }
    }
}

// ---------------------------------------------------------------------------
// MFMA flash attention (r5, proven 87.6us): async-DMA pipelined K/Vt LDS
// double-buffer, source-side swizzle, transposed-S, exp2 softmax, VALU-diet
// softmax (defer-max, packed f32, deferred l reduction), setprio on MFMA.
// ---------------------------------------------------------------------------
__global__ __launch_bounds__(256, 4) void attn_mfma(
    const ushort* __restrict__ Q, const ushort* __restrict__ K,
    const ushort* __restrict__ Vt, ushort* __restrict__ Y)
{
    __shared__ __align__(16) ushort Ks[2][64 * 64];
    __shared__ __align__(16) ushort Vs[2][64 * 64];
    __shared__ __align__(16) ushort Ps[64 * 64];

    const int tid = threadIdx.x;
    const int bh = blockIdx.x, bx = blockIdx.y;
    const int w = tid >> 6, lane = tid & 63, l15 = lane & 15, qd = lane >> 4;
    const size_t base = (size_t)bh * Tn * Dn;
    const int lrow = lane >> 3;                   // 0..7
    const int lchunk = (lane & 7) ^ (lrow & 7);   // source-side swizzle
    const int q_l = w * 16 + l15;
    const int frow = q_l * 64;
    const int fx0 = ((0 * 4 + qd) ^ (l15 & 7)) * 8;
    const int fx1 = ((1 * 4 + qd) ^ (l15 & 7)) * 8;
    const int b = bh >> 4, h = bh & 15;

    // staging sources: wave w stages rows w*16 .. w*16+15 of each tile
    const ushort* Kg = K + base + (size_t)(w * 16 + lrow) * Dn + lchunk * 8;
    const ushort* Vg = Vt + base + (size_t)(w * 16 + lrow) * Tn + lchunk * 8;
    // Q fragments direct from global
    const ushort* Qp = Q + base + (size_t)l15 * Dn + qd * 8;

#pragma unroll
    for (int half = 0; half < 2; ++half) {
        const int qt = half ? (31 - bx) : bx;

        const ushort* qrow = Qp + (size_t)(qt * 64 + w * 16) * Dn;
        s16x8 qf0 = *(const s16x8*)(qrow);
        s16x8 qf1 = *(const s16x8*)(qrow + 32);

        __syncthreads();   // previous half's LDS reads complete
        // issue DMA for tile 0 -> buffer 0
#pragma unroll
        for (int t = 0; t < 2; ++t) {
            gl_lds16(Kg + (size_t)(t * 8) * Dn, &Ks[0][(w * 16 + t * 8) * 64]);
            gl_lds16(Vg + (size_t)(t * 8) * Tn, &Vs[0][(w * 16 + t * 8) * 64]);
        }

        float m_run = -1e30f, l_run = 0.f;   // l_run: per-lane partial sum
        f32x4 o[4] = {};   // O^T[d=dt*16+qd*4+r][q=l15]

        for (int kt = 0; kt <= qt; ++kt) {
            const int buf = kt & 1;
            __syncthreads();   // drains own vmcnt -> tile kt ready; buf^1 free
            if (kt < qt) {     // issue DMA for kt+1 -> buf^1 (overlaps compute)
#pragma unroll
                for (int t = 0; t < 2; ++t) {
                    gl_lds16(Kg + (size_t)((kt + 1) * 64 + t * 8) * Dn,
                             &Ks[buf ^ 1][(w * 16 + t * 8) * 64]);
                    gl_lds16(Vg + (size_t)(t * 8) * Tn + (kt + 1) * 64,
                             &Vs[buf ^ 1][(w * 16 + t * 8) * 64]);
                }
            }

            // S^T = K·Q^T (exp2 domain via pre-scaled Q)
            f32x4 s[4] = {};
            __builtin_amdgcn_s_setprio(1);
#pragma unroll
            for (int nt = 0; nt < 4; ++nt) {
                s16x8 kf = *(const s16x8*)&Ks[buf][(nt * 16 + l15) * 64 + fx0];
                s[nt] = MFMA_BF16(kf, qf0, s[nt]);
            }
#pragma unroll
            for (int nt = 0; nt < 4; ++nt) {
                s16x8 kf = *(const s16x8*)&Ks[buf][(nt * 16 + l15) * 64 + fx1];
                s[nt] = MFMA_BF16(kf, qf1, s[nt]);
            }
            __builtin_amdgcn_s_setprio(0);

            if (kt == qt) {
#pragma unroll
                for (int nt = 0; nt < 4; ++nt)
#pragma unroll
                    for (int r = 0; r < 4; ++r)
                        if (nt * 16 + qd * 4 + r > q_l) s[nt][r] = -1e30f;
            }

            // per-query max: depth-4 tree (fuses to v_max3) + 2 shuffles
            float a0 = fmaxf(fmaxf(s[0][0], s[0][1]), fmaxf(s[0][2], s[0][3]));
            float a1 = fmaxf(fmaxf(s[1][0], s[1][1]), fmaxf(s[1][2], s[1][3]));
            float a2 = fmaxf(fmaxf(s[2][0], s[2][1]), fmaxf(s[2][2], s[2][3]));
            float a3 = fmaxf(fmaxf(s[3][0], s[3][1]), fmaxf(s[3][2], s[3][3]));
            float mx = fmaxf(fmaxf(a0, a1), fmaxf(a2, a3));
            mx = fmaxf(mx, __shfl_xor(mx, 16));
            mx = fmaxf(mx, __shfl_xor(mx, 32));

            // defer-max: only rescale when the max grew by > 8 (2^8 bound)
            if (!__all(mx <= m_run + 8.f)) {
                float m_new = fmaxf(m_run, mx);
                float alpha = exp2f(m_run - m_new);
                m_run = m_new;
                l_run *= alpha;
                f32x2 aa = {alpha, alpha};
#pragma unroll
                for (int dt = 0; dt < 4; ++dt) {
                    o[dt].lo = pk_mul(o[dt].lo, aa);
                    o[dt].hi = pk_mul(o[dt].hi, aa);
                }
            }

            // p = exp2(s - m_run); packed subtract / packed l-accum
            const f32x2 negm = {-m_run, -m_run};
            f32x2 lac0 = {0.f, 0.f}, lac1 = {0.f, 0.f};
#pragma unroll
            for (int nt = 0; nt < 4; ++nt) {
                s[nt].lo = pk_add(s[nt].lo, negm);
                s[nt].hi = pk_add(s[nt].hi, negm);
                s[nt][0] = exp2f(s[nt][0]);
                s[nt][1] = exp2f(s[nt][1]);
                s[nt][2] = exp2f(s[nt][2]);
                s[nt][3] = exp2f(s[nt][3]);
                lac0 = pk_add(lac0, s[nt].lo);
                lac1 = pk_add(lac1, s[nt].hi);
            }
            lac0 = pk_add(lac0, lac1);
            l_run += lac0[0] + lac0[1];

            // P^T -> wave-private LDS rows (packed bf16 pairs)
#pragma unroll
            for (int nt = 0; nt < 4; ++nt) {
                uint2 pk;
                pk.x = pkbf(s[nt][0], s[nt][1]);
                pk.y = pkbf(s[nt][2], s[nt][3]);
                const int pc = 2 * nt + (qd >> 1), po = (qd & 1) * 4;
                *(uint2*)&Ps[frow + ((pc ^ (l15 & 7)) * 8) + po] = pk;
            }

            // O^T += V^T · P^T  (same-wave LDS round trip; no barrier)
            {
                s16x8 pb = *(const s16x8*)&Ps[frow + fx0];
                __builtin_amdgcn_s_setprio(1);
#pragma unroll
                for (int dt = 0; dt < 4; ++dt) {
                    s16x8 vf = *(const s16x8*)&Vs[buf][(dt * 16 + l15) * 64 + fx0];
                    o[dt] = MFMA_BF16(vf, pb, o[dt]);
                }
                pb = *(const s16x8*)&Ps[frow + fx1];
#pragma unroll
                for (int dt = 0; dt < 4; ++dt) {
                    s16x8 vf = *(const s16x8*)&Vs[buf][(dt * 16 + l15) * 64 + fx1];
                    o[dt] = MFMA_BF16(vf, pb, o[dt]);
                }
                __builtin_amdgcn_s_setprio(0);
            }
        }

        // epilogue: reduce partial l across the 4-lane query group, then
        // O^T[d][q=l15] -> Y[b, t=q_global, h*64+d]
        float lt = l_run;
        lt += __shfl_xor(lt, 16);
        lt += __shfl_xor(lt, 32);
        const float inv = 1.f / lt;
        const int t_g = qt * 64 + w * 16 + l15;
        ushort* yp = Y + ((size_t)(b * Tn + t_g)) * Cn + h * Dn + qd * 4;
#pragma unroll
        for (int dt = 0; dt < 4; ++dt) {
            uint2 pk;
            pk.x = pkbf(o[dt][0] * inv, o[dt][1] * inv);
            pk.y = pkbf(o[dt][2] * inv, o[dt][3] * inv);
            *(uint2*)(yp + dt * 16) = pk;
        }
    }
}

// ---------------------------------------------------------------------------
// Proj GEMM: Y [8192][1024] bf16, Wt [1024][1024] bf16 -> out fp32
// ---------------------------------------------------------------------------
__global__ __launch_bounds__(256) void proj_gemm_mfma(
    const ushort* __restrict__ A, const ushort* __restrict__ Bt,
    const float* __restrict__ bias, float* __restrict__ out)
{
    __shared__ __align__(16) ushort As[128 * 64];
    __shared__ __align__(16) ushort Bs[128 * 64];
    const int tid = threadIdx.x;
    const int m0 = blockIdx.x * 128, n0 = blockIdx.y * 128;
    const int w = tid >> 6, lane = tid & 63, l15 = lane & 15, qd = lane >> 4;
    const int wm = (w >> 1) * 64, wn = (w & 1) * 64;
    const int lrow = lane >> 3;
    const int lchunk = (lane & 7) ^ (lrow & 7);

    const ushort* gA = A + (size_t)(m0 + w * 32 + lrow) * Cn + lchunk * 8;
    const ushort* gB = Bt + (size_t)(n0 + w * 32 + lrow) * Cn + lchunk * 8;
    ushort* lA = &As[(w * 32) * 64];
    ushort* lB = &Bs[(w * 32) * 64];

    f32x4 acc[4][4] = {};

    for (int k0 = 0; k0 < Cn; k0 += 64) {
        __syncthreads();
#pragma unroll
        for (int t = 0; t < 4; ++t) {
            gl_lds16(gA + (size_t)t * 8 * Cn + k0, lA + t * 8 * 64);
            gl_lds16(gB + (size_t)t * 8 * Cn + k0, lB + t * 8 * 64);
        }
        __syncthreads();
#pragma unroll
        for (int ks = 0; ks < 2; ++ks) {
            const int xs = (((ks * 4 + qd) ^ (l15 & 7))) * 8;
            s16x8 af[4], bfr[4];
#pragma unroll
            for (int i = 0; i < 4; ++i) {
                af[i]  = *(const s16x8*)&As[(wm + i * 16 + l15) * 64 + xs];
                bfr[i] = *(const s16x8*)&Bs[(wn + i * 16 + l15) * 64 + xs];
            }
#pragma unroll
            for (int mt = 0; mt < 4; ++mt)
#pragma unroll
                for (int nt = 0; nt < 4; ++nt)
                    acc[mt][nt] = MFMA_BF16(af[mt], bfr[nt], acc[mt][nt]);
        }
    }

#pragma unroll
    for (int nt = 0; nt < 4; ++nt) {
        int n_g = n0 + wn + nt * 16 + l15;
        float bv = bias[n_g];
#pragma unroll
        for (int mt = 0; mt < 4; ++mt) {
#pragma unroll
            for (int r = 0; r < 4; ++r) {
                int m_g = m0 + wm + mt * 16 + qd * 4 + r;
                out[(size_t)m_g * Cn + n_g] = acc[mt][nt][r] + bv;
            }
        }
    }
}

// ---------------------------------------------------------------------------
extern "C" void kernel_launch(void* const* d_in, const int* in_sizes, int n_in,
                              void* d_out, int out_size, void* d_ws, size_t ws_size,
                              hipStream_t stream) {
    const float* x      = (const float*)d_in[0];
    const float* W_attn = (const float*)d_in[1];
    const float* b_attn = (const float*)d_in[2];
    const float* W_proj = (const float*)d_in[3];
    const float* b_proj = (const float*)d_in[4];
    float* out = (float*)d_out;

    // ws: Q, K [B,H,T,D] bf16; Vt [B,H,D,T] bf16 (written directly by qkv);
    //     Y [B,T,C] bf16
    constexpr size_t PER = (size_t)Mn * Cn;  // 8388608 elems
    ushort* Qb  = (ushort*)d_ws;
    ushort* Kb  = Qb + PER;
    ushort* Vtb = Kb + PER;
    ushort* Yb  = Vtb + PER;

    // d_out as scratch (33.5 MB): WtA [3072][1024] bf16 + x_bf [8192][1024] bf16
    ushort* WtA  = (ushort*)d_out;
    ushort* x_bf = WtA + (size_t)Nqkv * Cn;
    ushort* WtP  = Qb;                 // reuses Q buffer (dead after attention)

    conv_bf16_kernel<<<1024, 256, 0, stream>>>(x, x_bf, (int)(PER / 4));
    transpose_cvt_kernel<<<dim3(Nqkv / 64, Cn / 64), 256, 0, stream>>>(
        W_attn, WtA, Cn, Nqkv);
    qkv_gemm_mfma<<<dim3(Mn / 128, Nqkv / 128), 256, 0, stream>>>(
        x_bf, WtA, b_attn, Qb, Kb, Vtb);
    attn_mfma<<<dim3(Bn * Hn, 16), 256, 0, stream>>>(Qb, Kb, Vtb, Yb);
    transpose_cvt_kernel<<<dim3(Cn / 64, Cn / 64), 256, 0, stream>>>(
        W_proj, WtP, Cn, Cn);
    proj_gemm_mfma<<<dim3(Mn / 128, Cn / 128), 256, 0, stream>>>(
        Yb, WtP, b_proj, out);
}

// Round 8
// 245.832 us; speedup vs baseline: 1.4480x; 1.0338x over previous
//
#include <hip/hip_runtime.h>
#include <hip/hip_bf16.h>

typedef short s16x8 __attribute__((ext_vector_type(8)));
typedef float f32x4 __attribute__((ext_vector_type(4)));
typedef float f32x2 __attribute__((ext_vector_type(2)));

#define MFMA_BF16(A, B, C) __builtin_amdgcn_mfma_f32_16x16x32_bf16(A, B, C, 0, 0, 0)

constexpr int Bn = 4, Tn = 2048, Cn = 1024, Hn = 16, Dn = 64;
constexpr int Mn = Bn * Tn;      // 8192
constexpr int Nqkv = 3 * Cn;     // 3072
constexpr float SC = 0.125f * 1.44269504089f;  // 1/sqrt(D) * log2(e)

__device__ __forceinline__ ushort f2bfu(float f) {
    __hip_bfloat16 h = __float2bfloat16(f);
    return *reinterpret_cast<ushort*>(&h);
}
__device__ __forceinline__ uint pkbf(float a, float b) {
    __hip_bfloat162 h = __float22bfloat162_rn(make_float2(a, b));
    return *reinterpret_cast<uint*>(&h);
}

// packed fp32 VALU (full-rate on CDNA4)
__device__ __forceinline__ f32x2 pk_add(f32x2 a, f32x2 b) {
    f32x2 d; asm("v_pk_add_f32 %0, %1, %2" : "=v"(d) : "v"(a), "v"(b)); return d;
}
__device__ __forceinline__ f32x2 pk_mul(f32x2 a, f32x2 b) {
    f32x2 d; asm("v_pk_mul_f32 %0, %1, %2" : "=v"(d) : "v"(a), "v"(b)); return d;
}

// async global->LDS, 16B per lane; LDS dest = wave-uniform base + lane*16.
__device__ __forceinline__ void gl_lds16(const void* g, void* l) {
    __builtin_amdgcn_global_load_lds(
        (const __attribute__((address_space(1))) void*)(uintptr_t)g,
        (__attribute__((address_space(3))) void*)(uint32_t)(uintptr_t)l,
        16, 0, 0);
}

// ---------------------------------------------------------------------------
// fp32 -> bf16 elementwise (x)
// ---------------------------------------------------------------------------
__global__ __launch_bounds__(256) void conv_bf16_kernel(
    const float* __restrict__ src, ushort* __restrict__ dst, int n4)
{
    int i = blockIdx.x * blockDim.x + threadIdx.x;
    int stride = gridDim.x * blockDim.x;
    for (; i < n4; i += stride) {
        float4 v = ((const float4*)src)[i];
        ushort4 o;
        o.x = f2bfu(v.x); o.y = f2bfu(v.y); o.z = f2bfu(v.z); o.w = f2bfu(v.w);
        ((ushort4*)dst)[i] = o;
    }
}

// ---------------------------------------------------------------------------
// W [K][N] fp32  ->  Wt [N][K] bf16   (64x64 tiles via LDS)
// ---------------------------------------------------------------------------
__global__ __launch_bounds__(256) void transpose_cvt_kernel(
    const float* __restrict__ W, ushort* __restrict__ Wt, int K, int N)
{
    __shared__ __align__(16) float Ls[64][68];
    const int t = threadIdx.x;
    const int n0 = blockIdx.x * 64, k0 = blockIdx.y * 64;
#pragma unroll
    for (int p = 0; p < 4; ++p) {
        int r = (t >> 4) + p * 16;
        int c = (t & 15) * 4;
        *(float4*)&Ls[r][c] = *(const float4*)&W[(size_t)(k0 + r) * N + n0 + c];
    }
    __syncthreads();
    const int n = t >> 2;
    const int ks = (t & 3) * 16;
    union { ushort s[16]; uint4 u[2]; } tmp;
#pragma unroll
    for (int j = 0; j < 16; ++j) tmp.s[j] = f2bfu(Ls[ks + j][n]);
    uint4* dp = (uint4*)&Wt[(size_t)(n0 + n) * K + k0 + ks];
    dp[0] = tmp.u[0];
    dp[1] = tmp.u[1];
}

// ---------------------------------------------------------------------------
// Pipelined GEMM main-loop building blocks (T3/T4): 1-ahead double buffer,
// counted vmcnt (never 0 in steady state), raw s_barrier (no compiler drain).
// Per wave per K-step: 8 gl_lds (4 A + 4 B). In flight at top of iter s:
// steps {s, s+1} = 16 loads -> vmcnt(8) retires exactly step s (FIFO).
// ---------------------------------------------------------------------------
#define GSTAGE(s, b)                                                          \
    _Pragma("unroll")                                                         \
    for (int t_ = 0; t_ < 4; ++t_) {                                          \
        gl_lds16(gA + (size_t)t_ * 8 * Cn + (s) * 64,                         \
                 &As[b][(w * 32 + t_ * 8) * 64]);                             \
        gl_lds16(gB + (size_t)t_ * 8 * Cn + (s) * 64,                         \
                 &Bs[b][(w * 32 + t_ * 8) * 64]);                             \
    }

// ---------------------------------------------------------------------------
// QKV GEMM, pipelined. Q outputs pre-scaled by SC (exp2 domain).
// Blocks are column-pure: Q/K standard epilogue; V swapped-orientation
// epilogue writing directly into Vt [bh][d][t] (r6-proven).
// ---------------------------------------------------------------------------
__global__ __launch_bounds__(256, 2) void qkv_gemm_mfma(
    const ushort* __restrict__ A, const ushort* __restrict__ Bt,
    const float* __restrict__ bias,
    ushort* __restrict__ Qo, ushort* __restrict__ Ko, ushort* __restrict__ Vo)
{
    __shared__ __align__(16) ushort As[2][128 * 64];   // 32KB
    __shared__ __align__(16) ushort Bs[2][128 * 64];   // 32KB
    const int tid = threadIdx.x;
    const int m0 = blockIdx.x * 128, n0 = blockIdx.y * 128;
    const int w = tid >> 6, lane = tid & 63, l15 = lane & 15, qd = lane >> 4;
    const int wm = (w >> 1) * 64, wn = (w & 1) * 64;
    const int lrow = lane >> 3;
    const int lchunk = (lane & 7) ^ (lrow & 7);

    const ushort* gA = A + (size_t)(m0 + w * 32 + lrow) * Cn + lchunk * 8;
    const ushort* gB = Bt + (size_t)(n0 + w * 32 + lrow) * Cn + lchunk * 8;

    f32x4 acc[4][4] = {};
    const bool isV = (n0 >= 2 * Cn);   // block-uniform

    GSTAGE(0, 0);
    GSTAGE(1, 1);

    for (int s = 0; s < 16; ++s) {
        if (s < 15) { asm volatile("s_waitcnt vmcnt(8)" ::: "memory"); }
        else        { asm volatile("s_waitcnt vmcnt(0)" ::: "memory"); }
        __builtin_amdgcn_sched_barrier(0);
        __builtin_amdgcn_s_barrier();        // (A) step-s tile visible to all
        __builtin_amdgcn_sched_barrier(0);

        const ushort* a_ = As[s & 1];
        const ushort* b_ = Bs[s & 1];
        __builtin_amdgcn_s_setprio(1);
#pragma unroll
        for (int ks = 0; ks < 2; ++ks) {
            const int xs = (((ks * 4 + qd) ^ (l15 & 7))) * 8;
            s16x8 af[4], bfr[4];
#pragma unroll
            for (int i = 0; i < 4; ++i) {
                af[i]  = *(const s16x8*)&a_[(wm + i * 16 + l15) * 64 + xs];
                bfr[i] = *(const s16x8*)&b_[(wn + i * 16 + l15) * 64 + xs];
            }
            if (!isV) {
#pragma unroll
                for (int mt = 0; mt < 4; ++mt)
#pragma unroll
                    for (int nt = 0; nt < 4; ++nt)
                        acc[mt][nt] = MFMA_BF16(af[mt], bfr[nt], acc[mt][nt]);
            } else {
#pragma unroll
                for (int mt = 0; mt < 4; ++mt)
#pragma unroll
                    for (int nt = 0; nt < 4; ++nt)
                        acc[nt][mt] = MFMA_BF16(bfr[nt], af[mt], acc[nt][mt]);
            }
        }
        __builtin_amdgcn_s_setprio(0);

        __builtin_amdgcn_sched_barrier(0);
        __builtin_amdgcn_s_barrier();        // (B) all waves done reading buf
        __builtin_amdgcn_sched_barrier(0);
        if (s + 2 < 16) { GSTAGE(s + 2, s & 1); }
    }

    if (!isV) {
        // ---- Q/K epilogue (standard orientation, r1/r6-proven) ----
        const int sel = n0 >> 10;               // 0=Q, 1=K (uniform)
        ushort* O = (sel == 0) ? Qo : Ko;
        const float scl = (sel == 0) ? SC : 1.0f;
#pragma unroll
        for (int nt = 0; nt < 4; ++nt) {
            const int n_g = n0 + wn + nt * 16 + l15;
            const float bv = bias[n_g];
            const int h = (n_g >> 6) & 15;
            const int d = n_g & 63;
#pragma unroll
            for (int mt = 0; mt < 4; ++mt) {
#pragma unroll
                for (int r = 0; r < 4; ++r) {
                    const int m_g = m0 + wm + mt * 16 + qd * 4 + r;
                    const int b = m_g >> 11, t = m_g & 2047;
                    O[(((size_t)(b * Hn + h) * Tn + t) << 6) + d] =
                        f2bfu((acc[mt][nt][r] + bv) * scl);
                }
            }
        }
    } else {
        // ---- V epilogue: swapped orientation -> direct Vt [bh][d][t] ----
#pragma unroll
        for (int nt = 0; nt < 4; ++nt) {
            const int n_b = n0 + wn + nt * 16 + qd * 4;   // 4 consecutive d
            const float4 bv = *(const float4*)&bias[n_b];
            const int h = (n_b >> 6) & 15;
            const int d0 = n_b & 63;
#pragma unroll
            for (int mt = 0; mt < 4; ++mt) {
                const int m_g = m0 + wm + mt * 16 + l15;
                const int b = m_g >> 11, tt = m_g & 2047;
                const size_t rowb = (size_t)(b * Hn + h) * Dn;
                Vo[(rowb + d0 + 0) * Tn + tt] = f2bfu(acc[nt][mt][0] + bv.x);
                Vo[(rowb + d0 + 1) * Tn + tt] = f2bfu(acc[nt][mt][1] + bv.y);
                Vo[(rowb + d0 + 2) * Tn + tt] = f2bfu(acc[nt][mt][2] + bv.z);
                Vo[(rowb + d0 + 3) * Tn + tt] = f2bfu(acc[nt][mt][3] + bv.w);
            }
        }
    }
}

// ---------------------------------------------------------------------------
// MFMA flash attention (r5/r6, proven ~88us): async-DMA pipelined K/Vt LDS
// double-buffer, source-side swizzle, transposed-S, exp2 softmax, VALU-diet
// softmax (defer-max, packed f32, deferred l reduction), setprio on MFMA.
// ---------------------------------------------------------------------------
__global__ __launch_bounds__(256, 4) void attn_mfma(
    const ushort* __restrict__ Q, const ushort* __restrict__ K,
    const ushort* __restrict__ Vt, ushort* __restrict__ Y)
{
    __shared__ __align__(16) ushort Ks[2][64 * 64];
    __shared__ __align__(16) ushort Vs[2][64 * 64];
    __shared__ __align__(16) ushort Ps[64 * 64];

    const int tid = threadIdx.x;
    const int bh = blockIdx.x, bx = blockIdx.y;
    const int w = tid >> 6, lane = tid & 63, l15 = lane & 15, qd = lane >> 4;
    const size_t base = (size_t)bh * Tn * Dn;
    const int lrow = lane >> 3;                   // 0..7
    const int lchunk = (lane & 7) ^ (lrow & 7);   // source-side swizzle
    const int q_l = w * 16 + l15;
    const int frow = q_l * 64;
    const int fx0 = ((0 * 4 + qd) ^ (l15 & 7)) * 8;
    const int fx1 = ((1 * 4 + qd) ^ (l15 & 7)) * 8;
    const int b = bh >> 4, h = bh & 15;

    // staging sources: wave w stages rows w*16 .. w*16+15 of each tile
    const ushort* Kg = K + base + (size_t)(w * 16 + lrow) * Dn + lchunk * 8;
    const ushort* Vg = Vt + base + (size_t)(w * 16 + lrow) * Tn + lchunk * 8;
    // Q fragments direct from global
    const ushort* Qp = Q + base + (size_t)l15 * Dn + qd * 8;

#pragma unroll
    for (int half = 0; half < 2; ++half) {
        const int qt = half ? (31 - bx) : bx;

        const ushort* qrow = Qp + (size_t)(qt * 64 + w * 16) * Dn;
        s16x8 qf0 = *(const s16x8*)(qrow);
        s16x8 qf1 = *(const s16x8*)(qrow + 32);

        __syncthreads();   // previous half's LDS reads complete
        // issue DMA for tile 0 -> buffer 0
#pragma unroll
        for (int t = 0; t < 2; ++t) {
            gl_lds16(Kg + (size_t)(t * 8) * Dn, &Ks[0][(w * 16 + t * 8) * 64]);
            gl_lds16(Vg + (size_t)(t * 8) * Tn, &Vs[0][(w * 16 + t * 8) * 64]);
        }

        float m_run = -1e30f, l_run = 0.f;   // l_run: per-lane partial sum
        f32x4 o[4] = {};   // O^T[d=dt*16+qd*4+r][q=l15]

        for (int kt = 0; kt <= qt; ++kt) {
            const int buf = kt & 1;
            __syncthreads();   // drains own vmcnt -> tile kt ready; buf^1 free
            if (kt < qt) {     // issue DMA for kt+1 -> buf^1 (overlaps compute)
#pragma unroll
                for (int t = 0; t < 2; ++t) {
                    gl_lds16(Kg + (size_t)((kt + 1) * 64 + t * 8) * Dn,
                             &Ks[buf ^ 1][(w * 16 + t * 8) * 64]);
                    gl_lds16(Vg + (size_t)(t * 8) * Tn + (kt + 1) * 64,
                             &Vs[buf ^ 1][(w * 16 + t * 8) * 64]);
                }
            }

            // S^T = K·Q^T (exp2 domain via pre-scaled Q)
            f32x4 s[4] = {};
            __builtin_amdgcn_s_setprio(1);
#pragma unroll
            for (int nt = 0; nt < 4; ++nt) {
                s16x8 kf = *(const s16x8*)&Ks[buf][(nt * 16 + l15) * 64 + fx0];
                s[nt] = MFMA_BF16(kf, qf0, s[nt]);
            }
#pragma unroll
            for (int nt = 0; nt < 4; ++nt) {
                s16x8 kf = *(const s16x8*)&Ks[buf][(nt * 16 + l15) * 64 + fx1];
                s[nt] = MFMA_BF16(kf, qf1, s[nt]);
            }
            __builtin_amdgcn_s_setprio(0);

            if (kt == qt) {
#pragma unroll
                for (int nt = 0; nt < 4; ++nt)
#pragma unroll
                    for (int r = 0; r < 4; ++r)
                        if (nt * 16 + qd * 4 + r > q_l) s[nt][r] = -1e30f;
            }

            // per-query max: depth-4 tree (fuses to v_max3) + 2 shuffles
            float a0 = fmaxf(fmaxf(s[0][0], s[0][1]), fmaxf(s[0][2], s[0][3]));
            float a1 = fmaxf(fmaxf(s[1][0], s[1][1]), fmaxf(s[1][2], s[1][3]));
            float a2 = fmaxf(fmaxf(s[2][0], s[2][1]), fmaxf(s[2][2], s[2][3]));
            float a3 = fmaxf(fmaxf(s[3][0], s[3][1]), fmaxf(s[3][2], s[3][3]));
            float mx = fmaxf(fmaxf(a0, a1), fmaxf(a2, a3));
            mx = fmaxf(mx, __shfl_xor(mx, 16));
            mx = fmaxf(mx, __shfl_xor(mx, 32));

            // defer-max: only rescale when the max grew by > 8 (2^8 bound)
            if (!__all(mx <= m_run + 8.f)) {
                float m_new = fmaxf(m_run, mx);
                float alpha = exp2f(m_run - m_new);
                m_run = m_new;
                l_run *= alpha;
                f32x2 aa = {alpha, alpha};
#pragma unroll
                for (int dt = 0; dt < 4; ++dt) {
                    o[dt].lo = pk_mul(o[dt].lo, aa);
                    o[dt].hi = pk_mul(o[dt].hi, aa);
                }
            }

            // p = exp2(s - m_run); packed subtract / packed l-accum
            const f32x2 negm = {-m_run, -m_run};
            f32x2 lac0 = {0.f, 0.f}, lac1 = {0.f, 0.f};
#pragma unroll
            for (int nt = 0; nt < 4; ++nt) {
                s[nt].lo = pk_add(s[nt].lo, negm);
                s[nt].hi = pk_add(s[nt].hi, negm);
                s[nt][0] = exp2f(s[nt][0]);
                s[nt][1] = exp2f(s[nt][1]);
                s[nt][2] = exp2f(s[nt][2]);
                s[nt][3] = exp2f(s[nt][3]);
                lac0 = pk_add(lac0, s[nt].lo);
                lac1 = pk_add(lac1, s[nt].hi);
            }
            lac0 = pk_add(lac0, lac1);
            l_run += lac0[0] + lac0[1];

            // P^T -> wave-private LDS rows (packed bf16 pairs)
#pragma unroll
            for (int nt = 0; nt < 4; ++nt) {
                uint2 pk;
                pk.x = pkbf(s[nt][0], s[nt][1]);
                pk.y = pkbf(s[nt][2], s[nt][3]);
                const int pc = 2 * nt + (qd >> 1), po = (qd & 1) * 4;
                *(uint2*)&Ps[frow + ((pc ^ (l15 & 7)) * 8) + po] = pk;
            }

            // O^T += V^T · P^T  (same-wave LDS round trip; no barrier)
            {
                s16x8 pb = *(const s16x8*)&Ps[frow + fx0];
                __builtin_amdgcn_s_setprio(1);
#pragma unroll
                for (int dt = 0; dt < 4; ++dt) {
                    s16x8 vf = *(const s16x8*)&Vs[buf][(dt * 16 + l15) * 64 + fx0];
                    o[dt] = MFMA_BF16(vf, pb, o[dt]);
                }
                pb = *(const s16x8*)&Ps[frow + fx1];
#pragma unroll
                for (int dt = 0; dt < 4; ++dt) {
                    s16x8 vf = *(const s16x8*)&Vs[buf][(dt * 16 + l15) * 64 + fx1];
                    o[dt] = MFMA_BF16(vf, pb, o[dt]);
                }
                __builtin_amdgcn_s_setprio(0);
            }
        }

        // epilogue: reduce partial l across the 4-lane query group, then
        // O^T[d][q=l15] -> Y[b, t=q_global, h*64+d]
        float lt = l_run;
        lt += __shfl_xor(lt, 16);
        lt += __shfl_xor(lt, 32);
        const float inv = 1.f / lt;
        const int t_g = qt * 64 + w * 16 + l15;
        ushort* yp = Y + ((size_t)(b * Tn + t_g)) * Cn + h * Dn + qd * 4;
#pragma unroll
        for (int dt = 0; dt < 4; ++dt) {
            uint2 pk;
            pk.x = pkbf(o[dt][0] * inv, o[dt][1] * inv);
            pk.y = pkbf(o[dt][2] * inv, o[dt][3] * inv);
            *(uint2*)(yp + dt * 16) = pk;
        }
    }
}

// ---------------------------------------------------------------------------
// Proj GEMM, pipelined: Y [8192][1024] bf16, Wt [1024][1024] bf16 -> out fp32
// ---------------------------------------------------------------------------
__global__ __launch_bounds__(256, 2) void proj_gemm_mfma(
    const ushort* __restrict__ A, const ushort* __restrict__ Bt,
    const float* __restrict__ bias, float* __restrict__ out)
{
    __shared__ __align__(16) ushort As[2][128 * 64];
    __shared__ __align__(16) ushort Bs[2][128 * 64];
    const int tid = threadIdx.x;
    const int m0 = blockIdx.x * 128, n0 = blockIdx.y * 128;
    const int w = tid >> 6, lane = tid & 63, l15 = lane & 15, qd = lane >> 4;
    const int wm = (w >> 1) * 64, wn = (w & 1) * 64;
    const int lrow = lane >> 3;
    const int lchunk = (lane & 7) ^ (lrow & 7);

    const ushort* gA = A + (size_t)(m0 + w * 32 + lrow) * Cn + lchunk * 8;
    const ushort* gB = Bt + (size_t)(n0 + w * 32 + lrow) * Cn + lchunk * 8;

    f32x4 acc[4][4] = {};

    GSTAGE(0, 0);
    GSTAGE(1, 1);

    for (int s = 0; s < 16; ++s) {
        if (s < 15) { asm volatile("s_waitcnt vmcnt(8)" ::: "memory"); }
        else        { asm volatile("s_waitcnt vmcnt(0)" ::: "memory"); }
        __builtin_amdgcn_sched_barrier(0);
        __builtin_amdgcn_s_barrier();
        __builtin_amdgcn_sched_barrier(0);

        const ushort* a_ = As[s & 1];
        const ushort* b_ = Bs[s & 1];
        __builtin_amdgcn_s_setprio(1);
#pragma unroll
        for (int ks = 0; ks < 2; ++ks) {
            const int xs = (((ks * 4 + qd) ^ (l15 & 7))) * 8;
            s16x8 af[4], bfr[4];
#pragma unroll
            for (int i = 0; i < 4; ++i) {
                af[i]  = *(const s16x8*)&a_[(wm + i * 16 + l15) * 64 + xs];
                bfr[i] = *(const s16x8*)&b_[(wn + i * 16 + l15) * 64 + xs];
            }
#pragma unroll
            for (int mt = 0; mt < 4; ++mt)
#pragma unroll
                for (int nt = 0; nt < 4; ++nt)
                    acc[mt][nt] = MFMA_BF16(af[mt], bfr[nt], acc[mt][nt]);
        }
        __builtin_amdgcn_s_setprio(0);

        __builtin_amdgcn_sched_barrier(0);
        __builtin_amdgcn_s_barrier();
        __builtin_amdgcn_sched_barrier(0);
        if (s + 2 < 16) { GSTAGE(s + 2, s & 1); }
    }

#pragma unroll
    for (int nt = 0; nt < 4; ++nt) {
        int n_g = n0 + wn + nt * 16 + l15;
        float bv = bias[n_g];
#pragma unroll
        for (int mt = 0; mt < 4; ++mt) {
#pragma unroll
            for (int r = 0; r < 4; ++r) {
                int m_g = m0 + wm + mt * 16 + qd * 4 + r;
                out[(size_t)m_g * Cn + n_g] = acc[mt][nt][r] + bv;
            }
        }
    }
}

// ---------------------------------------------------------------------------
extern "C" void kernel_launch(void* const* d_in, const int* in_sizes, int n_in,
                              void* d_out, int out_size, void* d_ws, size_t ws_size,
                              hipStream_t stream) {
    const float* x      = (const float*)d_in[0];
    const float* W_attn = (const float*)d_in[1];
    const float* b_attn = (const float*)d_in[2];
    const float* W_proj = (const float*)d_in[3];
    const float* b_proj = (const float*)d_in[4];
    float* out = (float*)d_out;

    // ws: Q, K [B,H,T,D] bf16; Vt [B,H,D,T] bf16 (written directly by qkv);
    //     Y [B,T,C] bf16
    constexpr size_t PER = (size_t)Mn * Cn;  // 8388608 elems
    ushort* Qb  = (ushort*)d_ws;
    ushort* Kb  = Qb + PER;
    ushort* Vtb = Kb + PER;
    ushort* Yb  = Vtb + PER;

    // d_out as scratch (33.5 MB): WtA [3072][1024] bf16 + x_bf [8192][1024] bf16
    ushort* WtA  = (ushort*)d_out;
    ushort* x_bf = WtA + (size_t)Nqkv * Cn;
    ushort* WtP  = Qb;                 // reuses Q buffer (dead after attention)

    conv_bf16_kernel<<<1024, 256, 0, stream>>>(x, x_bf, (int)(PER / 4));
    transpose_cvt_kernel<<<dim3(Nqkv / 64, Cn / 64), 256, 0, stream>>>(
        W_attn, WtA, Cn, Nqkv);
    qkv_gemm_mfma<<<dim3(Mn / 128, Nqkv / 128), 256, 0, stream>>>(
        x_bf, WtA, b_attn, Qb, Kb, Vtb);
    attn_mfma<<<dim3(Bn * Hn, 16), 256, 0, stream>>>(Qb, Kb, Vtb, Yb);
    transpose_cvt_kernel<<<dim3(Cn / 64, Cn / 64), 256, 0, stream>>>(
        W_proj, WtP, Cn, Cn);
    proj_gemm_mfma<<<dim3(Mn / 128, Cn / 128), 256, 0, stream>>>(
        Yb, WtP, b_proj, out);
}